// Round 13
// baseline (1032.398 us; speedup 1.0000x reference)
//
#include <hip/hip_runtime.h>

#define N_NODES 20000
#define N_EDGES 320000
#define N_GRAPHS 64
#define HID 256
#define EB 64                               // edges per tile (320000 % 64 == 0)
#define NB (N_EDGES / EB)                   // 5000 tiles
#define TGRID 256                           // persistent blocks (1 per CU)
#define NBK 48                              // nodes per block in node_mfma

typedef __attribute__((ext_vector_type(8))) short bf16x8;
typedef __attribute__((ext_vector_type(4))) float f32x4;

// ---------------- helpers ----------------
__device__ __forceinline__ unsigned short bf16_rne(float f) {
  unsigned u = __float_as_uint(f);
  u = u + 0x7FFFu + ((u >> 16) & 1u);
  return (unsigned short)(u >> 16);
}

__device__ __forceinline__ unsigned int enc_f32(float v) {
  unsigned int bits = __float_as_uint(v);
  return (bits & 0x80000000u) ? ~bits : (bits | 0x80000000u);
}

__device__ __forceinline__ float dec_u32(unsigned int u) {
  if (u == 0u) return 0.f;   // never-written -> no in-edges -> 0
  unsigned int bits = (u & 0x80000000u) ? (u ^ 0x80000000u) : ~u;
  return __uint_as_float(bits);
}

// ---------------- CSR build (once per launch) ----------------
__global__ __launch_bounds__(256) void hist_kernel(const int* __restrict__ ei,
                                                   int* __restrict__ deg) {
  int e = blockIdx.x * 256 + threadIdx.x;
  if (e < N_EDGES) atomicAdd(&deg[ei[N_EDGES + e]], 1);
}

__global__ __launch_bounds__(256) void scan_kernel(const int* __restrict__ deg,
                                                   int* __restrict__ cursor) {
  __shared__ int part[256];
  const int tid = threadIdx.x;
  const int CH = (N_NODES + 255) / 256;
  int s = tid * CH;
  int e = s + CH; if (e > N_NODES) e = N_NODES; if (s > N_NODES) s = N_NODES;
  int sum = 0;
  for (int i = s; i < e; i++) sum += deg[i];
  part[tid] = sum;
  __syncthreads();
  for (int off = 1; off < 256; off <<= 1) {
    int v = (tid >= off) ? part[tid - off] : 0;
    __syncthreads();
    part[tid] += v;
    __syncthreads();
  }
  int prefix = (tid == 0) ? 0 : part[tid - 1];
  for (int i = s; i < e; i++) {
    cursor[i] = prefix;
    prefix += deg[i];
  }
}

__global__ __launch_bounds__(256) void scatter_kernel(const int* __restrict__ ei,
                                                      int* __restrict__ cursor,
                                                      int* __restrict__ csr_src,
                                                      int* __restrict__ csr_dst) {
  int e = blockIdx.x * 256 + threadIdx.x;
  if (e < N_EDGES) {
    int s = ei[e], d = ei[N_EDGES + e];
    int pos = atomicAdd(&cursor[d], 1);
    csr_src[pos] = s;
    csr_dst[pos] = d;
  }
}

// ---------------- fused weight prep ----------------
__global__ __launch_bounds__(256) void prep_weights_kernel(
    const float* __restrict__ w2_0, const float* __restrict__ w2_1,
    const float* __restrict__ w2_2,
    const float* __restrict__ w1_1, const float* __restrict__ w1_2,
    unsigned short* __restrict__ w2t_hi, unsigned short* __restrict__ w2t_lo,
    unsigned short* __restrict__ w1t_hi, unsigned short* __restrict__ w1t_lo) {
  const int b = blockIdx.x;
  const int k = threadIdx.x;
  if (b < 768) {
    int l = b >> 8, j = b & 255;
    const float* w2 = (l == 0) ? w2_0 : ((l == 1) ? w2_1 : w2_2);
    float v = w2[k * HID + j];
    unsigned short hi = bf16_rne(v);
    float rem = v - __uint_as_float(((unsigned)hi) << 16);
    w2t_hi[((size_t)l * HID + j) * HID + k] = hi;
    w2t_lo[((size_t)l * HID + j) * HID + k] = bf16_rne(rem);
  } else {
    int b2 = b - 768;
    int l = b2 >> 9, jj = b2 & 511;
    const float* w1 = (l == 0) ? w1_1 : w1_2;
    float v;
    if (jj < 256) v = w1[k * HID + jj] - w1[(k + 256) * HID + jj];
    else v = w1[(k + 256) * HID + (jj - 256)];
    unsigned short hi = bf16_rne(v);
    float rem = v - __uint_as_float(((unsigned)hi) << 16);
    w1t_hi[((size_t)l * 512 + jj) * HID + k] = hi;
    w1t_lo[((size_t)l * 512 + jj) * HID + k] = bf16_rne(rem);
  }
}

// ---------------- layer-0 node A/B (fp32, DIN=56) ----------------
__global__ __launch_bounds__(256) void node_ab_l0_kernel(
    const float* __restrict__ x,
    const float* __restrict__ w1, const float* __restrict__ b1,
    float* __restrict__ A, float* __restrict__ B) {
  const int DIN = 56;
  __shared__ float xs[32 * DIN];
  const int node0 = blockIdx.x * 32;
  const int j = threadIdx.x;
  for (int t = threadIdx.x; t < 32 * DIN; t += 256) {
    int r = t / DIN, c = t - r * DIN;
    int node = node0 + r;
    xs[t] = (node < N_NODES) ? x[node * DIN + c] : 0.f;
  }
  __syncthreads();
  float accA[32], accB[32];
#pragma unroll
  for (int i = 0; i < 32; i++) { accA[i] = 0.f; accB[i] = 0.f; }
  for (int k = 0; k < DIN; k++) {
    float wt = w1[k * HID + j];
    float wb = w1[(k + DIN) * HID + j];
    float wa = wt - wb;
#pragma unroll
    for (int i = 0; i < 32; i++) {
      float xv = xs[i * DIN + k];
      accA[i] = fmaf(xv, wa, accA[i]);
      accB[i] = fmaf(xv, wb, accB[i]);
    }
  }
  float bj = b1[j];
  for (int i = 0; i < 32; i++) {
    int node = node0 + i;
    if (node < N_NODES) {
      A[node * HID + j] = accA[i] + bj;
      B[node * HID + j] = accB[i];
    }
  }
}

// ---------------- layers 1/2 node A/B via MFMA (hi/lo split) -------------
__global__ __launch_bounds__(512, 2) void node_mfma_kernel(
    const unsigned int* __restrict__ agg,
    const unsigned short* __restrict__ w1t_hi,
    const unsigned short* __restrict__ w1t_lo,
    const float* __restrict__ b1,
    float* __restrict__ A, float* __restrict__ Bm) {
  __shared__ char sm[NBK * 1024];   // hi plane [48][512B] @0, lo @24576
  const int tid = threadIdx.x;
  const int lane = tid & 63;
  const int wid = tid >> 6;
  const int node0 = blockIdx.x * NBK;

#pragma unroll
  for (int rr = 0; rr < NBK / 8; rr++) {
    int row = wid * (NBK / 8) + rr;
    int node = node0 + row;
    unsigned long long hp = 0, lp = 0;
    if (node < N_NODES) {
      uint4 u = *(const uint4*)(agg + (size_t)node * HID + lane * 4);
      float f[4];
      f[0] = dec_u32(u.x); f[1] = dec_u32(u.y); f[2] = dec_u32(u.z); f[3] = dec_u32(u.w);
#pragma unroll
      for (int i = 0; i < 4; i++) {
        float v = f[i];
        unsigned hu = bf16_rne(v);
        float rem = v - __uint_as_float(hu << 16);
        unsigned lu = bf16_rne(rem);
        hp |= (unsigned long long)hu << (16 * i);
        lp |= (unsigned long long)lu << (16 * i);
      }
    }
    int byte = row * 512 + ((lane * 8) ^ ((row & 7) << 4));
    *(unsigned long long*)(sm + byte) = hp;
    *(unsigned long long*)(sm + NBK * 512 + byte) = lp;
  }
  __syncthreads();

  const int nbase = wid * 64;        // column base in [0,512)
  const int lr = lane & 15;
  const int lg = lane >> 4;
  f32x4 acc[3][4];
#pragma unroll
  for (int mt = 0; mt < 3; mt++)
#pragma unroll
    for (int nt = 0; nt < 4; nt++) acc[mt][nt] = (f32x4){0.f, 0.f, 0.f, 0.f};

#pragma unroll
  for (int ks = 0; ks < 8; ks++) {
    const int kb = ks * 32 + lg * 8;
    bf16x8 ah[3], al[3], bh[4], bl[4];
#pragma unroll
    for (int mt = 0; mt < 3; mt++) {
      int row = mt * 16 + lr;
      int byte = row * 512 + ((kb * 2) ^ ((row & 7) << 4));
      ah[mt] = *(const bf16x8*)(sm + byte);
      al[mt] = *(const bf16x8*)(sm + NBK * 512 + byte);
    }
#pragma unroll
    for (int nt = 0; nt < 4; nt++) {
      int col = nbase + nt * 16 + lr;
      bh[nt] = *(const bf16x8*)(w1t_hi + (size_t)col * HID + kb);
      bl[nt] = *(const bf16x8*)(w1t_lo + (size_t)col * HID + kb);
    }
#pragma unroll
    for (int mt = 0; mt < 3; mt++)
#pragma unroll
      for (int nt = 0; nt < 4; nt++) {
        acc[mt][nt] = __builtin_amdgcn_mfma_f32_16x16x32_bf16(ah[mt], bh[nt], acc[mt][nt], 0, 0, 0);
        acc[mt][nt] = __builtin_amdgcn_mfma_f32_16x16x32_bf16(ah[mt], bl[nt], acc[mt][nt], 0, 0, 0);
        acc[mt][nt] = __builtin_amdgcn_mfma_f32_16x16x32_bf16(al[mt], bh[nt], acc[mt][nt], 0, 0, 0);
      }
  }

  const bool isA = (nbase < 256);
  float* dst = isA ? A : Bm;
  const int cb = isA ? nbase : (nbase - 256);
  float bv[4];
#pragma unroll
  for (int nt = 0; nt < 4; nt++)
    bv[nt] = isA ? b1[nbase + nt * 16 + lr] : 0.f;
#pragma unroll
  for (int mt = 0; mt < 3; mt++)
#pragma unroll
    for (int r = 0; r < 4; r++) {
      int row = mt * 16 + lg * 4 + r;
      int node = node0 + row;
      if (node < N_NODES) {
#pragma unroll
        for (int nt = 0; nt < 4; nt++)
          dst[(size_t)node * HID + cb + nt * 16 + lr] = acc[mt][nt][r] + bv[nt];
      }
    }
}

// ---------------- edge MLP: persistent blocks, w2 in REGISTERS ----------
// Each block (1/CU, 8 waves) loads its waves' w2 slices (32 cols x 256 k x
// hi/lo = 128 VGPR/lane) ONCE, then grid-strides over ~20 edge tiles.
// w2 L2 traffic: 1.28 GB -> 65 MB per dispatch.
__global__ __launch_bounds__(512, 1) void edge_mfma_kernel(
    const int* __restrict__ csr_src, const int* __restrict__ csr_dst,
    const float* __restrict__ A, const float* __restrict__ Bm,
    const unsigned short* __restrict__ w2t_hi,
    const unsigned short* __restrict__ w2t_lo,
    const float* __restrict__ b2,
    unsigned int* __restrict__ agg) {
  // LDS 64KB: hs_hi bf16[64][256] @0 (32KB), hs_lo @32768 (32KB);
  // OUT f32[64][256] (64KB) aliases after the MFMA barrier.
  __shared__ char sm[EB * 1024];
  const int tid = threadIdx.x;
  const int lane = tid & 63;
  const int wid = tid >> 6;            // 0..7
  const int lr = lane & 15;
  const int lg = lane >> 4;
  const int nbase = wid * 32;

  // ---- load this wave's w2 slice into registers (once per block) ----
  bf16x8 bh[2][8], bl[2][8];
#pragma unroll
  for (int nt = 0; nt < 2; nt++)
#pragma unroll
    for (int ks = 0; ks < 8; ks++) {
      int col = nbase + nt * 16 + lr;
      int kb = ks * 32 + lg * 8;
      bh[nt][ks] = *(const bf16x8*)(w2t_hi + (size_t)col * HID + kb);
      bl[nt][ks] = *(const bf16x8*)(w2t_lo + (size_t)col * HID + kb);
    }

  const float b2j = b2[tid & 255];

  for (int tile = blockIdx.x; tile < NB; tile += TGRID) {
    const int e0 = tile * EB;
    __syncthreads();   // prev iteration's OUT reads done before hs overwrite

    // ---- gather + relu + hi/lo split: 8 edges/wave, dst-run A reuse ----
    {
      float4 av = {0.f, 0.f, 0.f, 0.f};
      int dprev = -1;
#pragma unroll
      for (int q = 0; q < 8; q++) {
        int rep = wid * 8 + q;
        int d = csr_dst[e0 + rep];     // wave-uniform -> scalar load
        int s = csr_src[e0 + rep];
        if (d != dprev) {              // wave-uniform branch
          av = *(const float4*)(A + (size_t)d * HID + lane * 4);
          dprev = d;
        }
        float4 bv = *(const float4*)(Bm + (size_t)s * HID + lane * 4);
        float va[4], vb[4];
        *(float4*)va = av; *(float4*)vb = bv;
        unsigned long long hp = 0, lp = 0;
#pragma unroll
        for (int i = 0; i < 4; i++) {
          float v = fmaxf(va[i] + vb[i], 0.f);
          unsigned hu = bf16_rne(v);
          float rem = v - __uint_as_float(hu << 16);
          unsigned lu = bf16_rne(rem);
          hp |= (unsigned long long)hu << (16 * i);
          lp |= (unsigned long long)lu << (16 * i);
        }
        int byte = rep * 512 + ((lane * 8) ^ ((rep & 7) << 4));
        *(unsigned long long*)(sm + byte) = hp;
        *(unsigned long long*)(sm + EB * 512 + byte) = lp;
      }
    }
    __syncthreads();

    // ---- MFMA: wave owns cols [wid*32,+32); w2 operands from registers ----
    f32x4 acc[4][2];
#pragma unroll
    for (int mt = 0; mt < 4; mt++)
#pragma unroll
      for (int nt = 0; nt < 2; nt++) acc[mt][nt] = (f32x4){0.f, 0.f, 0.f, 0.f};

    __builtin_amdgcn_s_setprio(1);
#pragma unroll
    for (int ks = 0; ks < 8; ks++) {
      const int kb = ks * 32 + lg * 8;
      bf16x8 ah[4], al[4];
#pragma unroll
      for (int mt = 0; mt < 4; mt++) {
        int row = mt * 16 + lr;
        int byte = row * 512 + ((kb * 2) ^ ((row & 7) << 4));
        ah[mt] = *(const bf16x8*)(sm + byte);
        al[mt] = *(const bf16x8*)(sm + EB * 512 + byte);
      }
#pragma unroll
      for (int mt = 0; mt < 4; mt++)
#pragma unroll
        for (int nt = 0; nt < 2; nt++) {
          acc[mt][nt] = __builtin_amdgcn_mfma_f32_16x16x32_bf16(ah[mt], bh[nt][ks], acc[mt][nt], 0, 0, 0);
          acc[mt][nt] = __builtin_amdgcn_mfma_f32_16x16x32_bf16(ah[mt], bl[nt][ks], acc[mt][nt], 0, 0, 0);
          acc[mt][nt] = __builtin_amdgcn_mfma_f32_16x16x32_bf16(al[mt], bh[nt][ks], acc[mt][nt], 0, 0, 0);
        }
    }
    __builtin_amdgcn_s_setprio(0);
    __syncthreads();   // all hs reads done; safe to overwrite with OUT

    // ---- spill frags to LDS OUT (col bit4 swizzle keyed on row bit2) ----
    float* OUT = (float*)sm;
#pragma unroll
    for (int mt = 0; mt < 4; mt++)
#pragma unroll
      for (int nt = 0; nt < 2; nt++)
#pragma unroll
        for (int r = 0; r < 4; r++) {
          int row = mt * 16 + lg * 4 + r;
          int col = nbase + nt * 16 + lr;
          int c2 = col ^ (((row >> 2) & 1) << 4);
          OUT[row * HID + c2] = acc[mt][nt][r];
        }
    __syncthreads();

    // ---- segmented max: 2 workers per column (edge halves) ----
    const int half = tid >> 8;         // 0/1
    const int j = tid & 255;
    const int elo = half * 32, ehi = elo + 32;
    const bool left_open  = (half == 0) ? true : (csr_dst[e0 + elo - 1] == csr_dst[e0 + elo]);
    const bool right_open = (half == 1) ? true : (csr_dst[e0 + ehi] == csr_dst[e0 + ehi - 1]);
    int prevd = csr_dst[e0 + elo];
    int segstart = elo;
    float run = -INFINITY;
    for (int e = elo; e < ehi; e++) {
      int d = csr_dst[e0 + e];         // uniform scalar load (L1-hot)
      if (d != prevd) {
        unsigned int enc = enc_f32(run + b2j);
        unsigned int* p = agg + (size_t)prevd * HID + j;
        if (segstart == elo && left_open) atomicMax(p, enc);
        else *p = enc;
        run = -INFINITY;
        segstart = e;
        prevd = d;
      }
      run = fmaxf(run, OUT[e * HID + (j ^ (((e >> 2) & 1) << 4))]);
    }
    {
      unsigned int enc = enc_f32(run + b2j);
      unsigned int* p = agg + (size_t)prevd * HID + j;
      if (right_open || (segstart == elo && left_open)) atomicMax(p, enc);
      else *p = enc;
    }
  }
}

// ---------------- fused pooling + MLP head ----------------
__device__ __forceinline__ int lower_bound_i(const int* __restrict__ arr, int n, int val) {
  int lo = 0, hi = n;
  while (lo < hi) {
    int mid = (lo + hi) >> 1;
    if (arr[mid] < val) lo = mid + 1; else hi = mid;
  }
  return lo;
}

__global__ __launch_bounds__(256) void pool_mlp_kernel(
    const unsigned int* __restrict__ agg, const int* __restrict__ batch,
    const float* __restrict__ wc1, const float* __restrict__ bc1,
    const float* __restrict__ wc2, const float* __restrict__ bc2,
    const float* __restrict__ wc3, const float* __restrict__ bc3,
    float* __restrict__ out) {
  const int g = blockIdx.x;
  const int j = threadIdx.x;
  __shared__ float gs[2 * HID];
  __shared__ float h1[HID];
  __shared__ float h2[64];
  int s = lower_bound_i(batch, N_NODES, g);
  int e = lower_bound_i(batch, N_NODES, g + 1);
  float sum = 0.f, mx = -INFINITY;
  for (int i = s; i < e; i++) {
    float v = dec_u32(agg[(size_t)i * HID + j]);
    sum += v;
    mx = fmaxf(mx, v);
  }
  int cnt = e - s;
  gs[j] = sum / fmaxf((float)cnt, 1.f);
  gs[HID + j] = (cnt > 0) ? mx : 0.f;
  __syncthreads();
  float acc = bc1[j];
  for (int k = 0; k < 2 * HID; k++) acc = fmaf(gs[k], wc1[k * HID + j], acc);
  h1[j] = fmaxf(acc, 0.f);
  __syncthreads();
  if (j < 64) {
    float a2 = bc2[j];
    for (int k = 0; k < HID; k++) a2 = fmaf(h1[k], wc2[k * 64 + j], a2);
    h2[j] = fmaxf(a2, 0.f);
  }
  __syncthreads();
  if (j == 0) {
    float a3 = bc3[0];
    for (int k = 0; k < 64; k++) a3 = fmaf(h2[k], wc3[k], a3);
    out[g] = a3;
  }
}

extern "C" void kernel_launch(void* const* d_in, const int* in_sizes, int n_in,
                              void* d_out, int out_size, void* d_ws, size_t ws_size,
                              hipStream_t stream) {
  const float* x      = (const float*)d_in[0];
  const int*   ei     = (const int*)d_in[1];
  const int*   batch  = (const int*)d_in[2];
  const float* w1[3]  = {(const float*)d_in[3], (const float*)d_in[7],  (const float*)d_in[11]};
  const float* b1[3]  = {(const float*)d_in[4], (const float*)d_in[8],  (const float*)d_in[12]};
  const float* w2[3]  = {(const float*)d_in[5], (const float*)d_in[9],  (const float*)d_in[13]};
  const float* b2[3]  = {(const float*)d_in[6], (const float*)d_in[10], (const float*)d_in[14]};
  const float* wc1 = (const float*)d_in[15];
  const float* bc1 = (const float*)d_in[16];
  const float* wc2 = (const float*)d_in[17];
  const float* bc2 = (const float*)d_in[18];
  const float* wc3 = (const float*)d_in[19];
  const float* bc3 = (const float*)d_in[20];
  float* out = (float*)d_out;

  char* ws = (char*)d_ws;
  size_t off = 0;
  auto walloc = [&](size_t bytes) -> void* {
    void* p = ws + off;
    off += (bytes + 255) & ~(size_t)255;
    return p;
  };
  const size_t nh = (size_t)N_NODES * HID;
  float*          A       = (float*)walloc(nh * sizeof(float));
  float*          Bm      = (float*)walloc(nh * sizeof(float));
  unsigned int*   AGG     = (unsigned int*)walloc(nh * sizeof(unsigned int));
  int*            deg     = (int*)walloc((size_t)N_NODES * sizeof(int));
  int*            cursor  = (int*)walloc((size_t)N_NODES * sizeof(int));
  int*            csr_src = (int*)walloc((size_t)N_EDGES * sizeof(int));
  int*            csr_dst = (int*)walloc((size_t)N_EDGES * sizeof(int));
  unsigned short* w2t_hi  = (unsigned short*)walloc((size_t)3 * HID * HID * sizeof(unsigned short));
  unsigned short* w2t_lo  = (unsigned short*)walloc((size_t)3 * HID * HID * sizeof(unsigned short));
  unsigned short* w1t_hi  = (unsigned short*)walloc((size_t)2 * 512 * HID * sizeof(unsigned short));
  unsigned short* w1t_lo  = (unsigned short*)walloc((size_t)2 * 512 * HID * sizeof(unsigned short));
  (void)ws_size; (void)in_sizes; (void)n_in; (void)out_size;

  // ---- one-time: weight prep + CSR build ----
  hipMemsetAsync(deg, 0, N_NODES * sizeof(int), stream);
  prep_weights_kernel<<<1792, 256, 0, stream>>>(w2[0], w2[1], w2[2], w1[1], w1[2],
                                                w2t_hi, w2t_lo, w1t_hi, w1t_lo);
  hist_kernel<<<(N_EDGES + 255) / 256, 256, 0, stream>>>(ei, deg);
  scan_kernel<<<1, 256, 0, stream>>>(deg, cursor);
  scatter_kernel<<<(N_EDGES + 255) / 256, 256, 0, stream>>>(ei, cursor, csr_src, csr_dst);

  for (int l = 0; l < 3; l++) {
    if (l == 0)
      node_ab_l0_kernel<<<N_NODES / 32, 256, 0, stream>>>(x, w1[0], b1[0], A, Bm);
    else
      node_mfma_kernel<<<(N_NODES + NBK - 1) / NBK, 512, 0, stream>>>(
          AGG, w1t_hi + (size_t)(l - 1) * 512 * HID, w1t_lo + (size_t)(l - 1) * 512 * HID,
          b1[l], A, Bm);
    hipMemsetAsync(AGG, 0, nh * sizeof(unsigned int), stream);
    edge_mfma_kernel<<<TGRID, 512, 0, stream>>>(csr_src, csr_dst, A, Bm,
                                                w2t_hi + (size_t)l * HID * HID,
                                                w2t_lo + (size_t)l * HID * HID,
                                                b2[l], AGG);
  }
  pool_mlp_kernel<<<N_GRAPHS, 256, 0, stream>>>(AGG, batch, wc1, bc1, wc2, bc2, wc3, bc3, out);
}

// Round 14
// 924.686 us; speedup vs baseline: 1.1165x; 1.1165x over previous
//
#include <hip/hip_runtime.h>

#define N_NODES 20000
#define N_EDGES 320000
#define N_GRAPHS 64
#define HID 256
#define EB 64                               // edges per tile (320000 % 64 == 0)
#define NB (N_EDGES / EB)                   // 5000 blocks
#define NBK 48                              // nodes per block in node_mfma

typedef __attribute__((ext_vector_type(8))) short bf16x8;
typedef __attribute__((ext_vector_type(4))) float f32x4;

// ---------------- helpers ----------------
__device__ __forceinline__ unsigned short bf16_rne(float f) {
  unsigned u = __float_as_uint(f);
  u = u + 0x7FFFu + ((u >> 16) & 1u);
  return (unsigned short)(u >> 16);
}

__device__ __forceinline__ unsigned int enc_f32(float v) {
  unsigned int bits = __float_as_uint(v);
  return (bits & 0x80000000u) ? ~bits : (bits | 0x80000000u);
}

__device__ __forceinline__ float dec_u32(unsigned int u) {
  if (u == 0u) return 0.f;   // never-written -> no in-edges -> 0
  unsigned int bits = (u & 0x80000000u) ? (u ^ 0x80000000u) : ~u;
  return __uint_as_float(bits);
}

// ---------------- CSR build (once per launch) ----------------
__global__ __launch_bounds__(256) void hist_kernel(const int* __restrict__ ei,
                                                   int* __restrict__ deg) {
  int e = blockIdx.x * 256 + threadIdx.x;
  if (e < N_EDGES) atomicAdd(&deg[ei[N_EDGES + e]], 1);
}

__global__ __launch_bounds__(256) void scan_kernel(const int* __restrict__ deg,
                                                   int* __restrict__ cursor) {
  __shared__ int part[256];
  const int tid = threadIdx.x;
  const int CH = (N_NODES + 255) / 256;
  int s = tid * CH;
  int e = s + CH; if (e > N_NODES) e = N_NODES; if (s > N_NODES) s = N_NODES;
  int sum = 0;
  for (int i = s; i < e; i++) sum += deg[i];
  part[tid] = sum;
  __syncthreads();
  for (int off = 1; off < 256; off <<= 1) {
    int v = (tid >= off) ? part[tid - off] : 0;
    __syncthreads();
    part[tid] += v;
    __syncthreads();
  }
  int prefix = (tid == 0) ? 0 : part[tid - 1];
  for (int i = s; i < e; i++) {
    cursor[i] = prefix;
    prefix += deg[i];
  }
}

__global__ __launch_bounds__(256) void scatter_kernel(const int* __restrict__ ei,
                                                      int* __restrict__ cursor,
                                                      int* __restrict__ csr_src,
                                                      int* __restrict__ csr_dst) {
  int e = blockIdx.x * 256 + threadIdx.x;
  if (e < N_EDGES) {
    int s = ei[e], d = ei[N_EDGES + e];
    int pos = atomicAdd(&cursor[d], 1);
    csr_src[pos] = s;
    csr_dst[pos] = d;
  }
}

// ---------------- fused weight prep ----------------
__global__ __launch_bounds__(256) void prep_weights_kernel(
    const float* __restrict__ w2_0, const float* __restrict__ w2_1,
    const float* __restrict__ w2_2,
    const float* __restrict__ w1_1, const float* __restrict__ w1_2,
    unsigned short* __restrict__ w2t_hi, unsigned short* __restrict__ w2t_lo,
    unsigned short* __restrict__ w1t_hi, unsigned short* __restrict__ w1t_lo) {
  const int b = blockIdx.x;
  const int k = threadIdx.x;
  if (b < 768) {
    int l = b >> 8, j = b & 255;
    const float* w2 = (l == 0) ? w2_0 : ((l == 1) ? w2_1 : w2_2);
    float v = w2[k * HID + j];
    unsigned short hi = bf16_rne(v);
    float rem = v - __uint_as_float(((unsigned)hi) << 16);
    w2t_hi[((size_t)l * HID + j) * HID + k] = hi;
    w2t_lo[((size_t)l * HID + j) * HID + k] = bf16_rne(rem);
  } else {
    int b2 = b - 768;
    int l = b2 >> 9, jj = b2 & 511;
    const float* w1 = (l == 0) ? w1_1 : w1_2;
    float v;
    if (jj < 256) v = w1[k * HID + jj] - w1[(k + 256) * HID + jj];
    else v = w1[(k + 256) * HID + (jj - 256)];
    unsigned short hi = bf16_rne(v);
    float rem = v - __uint_as_float(((unsigned)hi) << 16);
    w1t_hi[((size_t)l * 512 + jj) * HID + k] = hi;
    w1t_lo[((size_t)l * 512 + jj) * HID + k] = bf16_rne(rem);
  }
}

// ---------------- layer-0 node A/B (fp32, DIN=56) ----------------
__global__ __launch_bounds__(256) void node_ab_l0_kernel(
    const float* __restrict__ x,
    const float* __restrict__ w1, const float* __restrict__ b1,
    float* __restrict__ A, float* __restrict__ B) {
  const int DIN = 56;
  __shared__ float xs[32 * DIN];
  const int node0 = blockIdx.x * 32;
  const int j = threadIdx.x;
  for (int t = threadIdx.x; t < 32 * DIN; t += 256) {
    int r = t / DIN, c = t - r * DIN;
    int node = node0 + r;
    xs[t] = (node < N_NODES) ? x[node * DIN + c] : 0.f;
  }
  __syncthreads();
  float accA[32], accB[32];
#pragma unroll
  for (int i = 0; i < 32; i++) { accA[i] = 0.f; accB[i] = 0.f; }
  for (int k = 0; k < DIN; k++) {
    float wt = w1[k * HID + j];
    float wb = w1[(k + DIN) * HID + j];
    float wa = wt - wb;
#pragma unroll
    for (int i = 0; i < 32; i++) {
      float xv = xs[i * DIN + k];
      accA[i] = fmaf(xv, wa, accA[i]);
      accB[i] = fmaf(xv, wb, accB[i]);
    }
  }
  float bj = b1[j];
  for (int i = 0; i < 32; i++) {
    int node = node0 + i;
    if (node < N_NODES) {
      A[node * HID + j] = accA[i] + bj;
      B[node * HID + j] = accB[i];
    }
  }
}

// ---------------- layers 1/2 node A/B via MFMA (hi/lo split) -------------
__global__ __launch_bounds__(512, 2) void node_mfma_kernel(
    const unsigned int* __restrict__ agg,
    const unsigned short* __restrict__ w1t_hi,
    const unsigned short* __restrict__ w1t_lo,
    const float* __restrict__ b1,
    float* __restrict__ A, float* __restrict__ Bm) {
  __shared__ char sm[NBK * 1024];   // hi plane [48][512B] @0, lo @24576
  const int tid = threadIdx.x;
  const int lane = tid & 63;
  const int wid = tid >> 6;
  const int node0 = blockIdx.x * NBK;

#pragma unroll
  for (int rr = 0; rr < NBK / 8; rr++) {
    int row = wid * (NBK / 8) + rr;
    int node = node0 + row;
    unsigned long long hp = 0, lp = 0;
    if (node < N_NODES) {
      uint4 u = *(const uint4*)(agg + (size_t)node * HID + lane * 4);
      float f[4];
      f[0] = dec_u32(u.x); f[1] = dec_u32(u.y); f[2] = dec_u32(u.z); f[3] = dec_u32(u.w);
#pragma unroll
      for (int i = 0; i < 4; i++) {
        float v = f[i];
        unsigned hu = bf16_rne(v);
        float rem = v - __uint_as_float(hu << 16);
        unsigned lu = bf16_rne(rem);
        hp |= (unsigned long long)hu << (16 * i);
        lp |= (unsigned long long)lu << (16 * i);
      }
    }
    int byte = row * 512 + ((lane * 8) ^ ((row & 7) << 4));
    *(unsigned long long*)(sm + byte) = hp;
    *(unsigned long long*)(sm + NBK * 512 + byte) = lp;
  }
  __syncthreads();

  const int nbase = wid * 64;        // column base in [0,512)
  const int lr = lane & 15;
  const int lg = lane >> 4;
  f32x4 acc[3][4];
#pragma unroll
  for (int mt = 0; mt < 3; mt++)
#pragma unroll
    for (int nt = 0; nt < 4; nt++) acc[mt][nt] = (f32x4){0.f, 0.f, 0.f, 0.f};

#pragma unroll
  for (int ks = 0; ks < 8; ks++) {
    const int kb = ks * 32 + lg * 8;
    bf16x8 ah[3], al[3], bh[4], bl[4];
#pragma unroll
    for (int mt = 0; mt < 3; mt++) {
      int row = mt * 16 + lr;
      int byte = row * 512 + ((kb * 2) ^ ((row & 7) << 4));
      ah[mt] = *(const bf16x8*)(sm + byte);
      al[mt] = *(const bf16x8*)(sm + NBK * 512 + byte);
    }
#pragma unroll
    for (int nt = 0; nt < 4; nt++) {
      int col = nbase + nt * 16 + lr;
      bh[nt] = *(const bf16x8*)(w1t_hi + (size_t)col * HID + kb);
      bl[nt] = *(const bf16x8*)(w1t_lo + (size_t)col * HID + kb);
    }
#pragma unroll
    for (int mt = 0; mt < 3; mt++)
#pragma unroll
      for (int nt = 0; nt < 4; nt++) {
        acc[mt][nt] = __builtin_amdgcn_mfma_f32_16x16x32_bf16(ah[mt], bh[nt], acc[mt][nt], 0, 0, 0);
        acc[mt][nt] = __builtin_amdgcn_mfma_f32_16x16x32_bf16(ah[mt], bl[nt], acc[mt][nt], 0, 0, 0);
        acc[mt][nt] = __builtin_amdgcn_mfma_f32_16x16x32_bf16(al[mt], bh[nt], acc[mt][nt], 0, 0, 0);
      }
  }

  const bool isA = (nbase < 256);
  float* dst = isA ? A : Bm;
  const int cb = isA ? nbase : (nbase - 256);
  float bv[4];
#pragma unroll
  for (int nt = 0; nt < 4; nt++)
    bv[nt] = isA ? b1[nbase + nt * 16 + lr] : 0.f;
#pragma unroll
  for (int mt = 0; mt < 3; mt++)
#pragma unroll
    for (int r = 0; r < 4; r++) {
      int row = mt * 16 + lg * 4 + r;
      int node = node0 + row;
      if (node < N_NODES) {
#pragma unroll
        for (int nt = 0; nt < 4; nt++)
          dst[(size_t)node * HID + cb + nt * 16 + lr] = acc[mt][nt][r] + bv[nt];
      }
    }
}

// ---------------- edge MLP (MFMA hi/lo, EB=64, 8 waves 1mx8n) -----------
// Saturation model (R4-R12): T = bytes / 9.6 TB/s when waves/CU >= ~12.
// No w2 duplication (each wave owns 32 distinct cols = 4KB/edge w2),
// dst-run A reuse, LDS 64KB -> 2 blocks x 8 waves = 16 waves/CU.
// Best measured: 224 us/dispatch = 83% of the pure-bytes floor.
__global__ __launch_bounds__(512, 2) void edge_mfma_kernel(
    const int* __restrict__ csr_src, const int* __restrict__ csr_dst,
    const float* __restrict__ A, const float* __restrict__ Bm,
    const unsigned short* __restrict__ w2t_hi,
    const unsigned short* __restrict__ w2t_lo,
    const float* __restrict__ b2,
    unsigned int* __restrict__ agg) {
  // LDS 64KB: hs_hi bf16[64][256] @0 (32KB), hs_lo @32768 (32KB);
  // OUT f32[64][256] (64KB) aliases after the MFMA barrier.
  __shared__ char sm[EB * 1024];
  __shared__ int sdst[EB];
  __shared__ int ssrc[EB];
  const int tid = threadIdx.x;
  const int e0 = blockIdx.x * EB;
  if (tid < EB) { sdst[tid] = csr_dst[e0 + tid]; ssrc[tid] = csr_src[e0 + tid]; }
  __syncthreads();
  const int lane = tid & 63;
  const int wid = tid >> 6;            // 0..7

  // ---- gather + relu + hi/lo split: 8 edges per wave, dst-run A reuse ----
  {
    float4 av = {0.f, 0.f, 0.f, 0.f};
    int dprev = -1;
#pragma unroll
    for (int q = 0; q < 8; q++) {
      int rep = wid * 8 + q;
      int d = sdst[rep];               // wave-uniform (LDS broadcast)
      int s = ssrc[rep];
      if (d != dprev) {                // wave-uniform branch
        av = *(const float4*)(A + (size_t)d * HID + lane * 4);
        dprev = d;
      }
      float4 bv = *(const float4*)(Bm + (size_t)s * HID + lane * 4);
      float va[4], vb[4];
      *(float4*)va = av; *(float4*)vb = bv;
      unsigned long long hp = 0, lp = 0;
#pragma unroll
      for (int i = 0; i < 4; i++) {
        float v = fmaxf(va[i] + vb[i], 0.f);
        unsigned hu = bf16_rne(v);
        float rem = v - __uint_as_float(hu << 16);
        unsigned lu = bf16_rne(rem);
        hp |= (unsigned long long)hu << (16 * i);
        lp |= (unsigned long long)lu << (16 * i);
      }
      int byte = rep * 512 + ((lane * 8) ^ ((rep & 7) << 4));
      *(unsigned long long*)(sm + byte) = hp;
      *(unsigned long long*)(sm + EB * 512 + byte) = lp;
    }
  }
  __syncthreads();

  // ---- MFMA: wave wid owns cols [wid*32, +32); all 64 edges (4 m-tiles) ----
  const int nbase = wid * 32;
  const int lr = lane & 15;
  const int lg = lane >> 4;
  f32x4 acc[4][2];
#pragma unroll
  for (int mt = 0; mt < 4; mt++)
#pragma unroll
    for (int nt = 0; nt < 2; nt++) acc[mt][nt] = (f32x4){0.f, 0.f, 0.f, 0.f};

  __builtin_amdgcn_s_setprio(1);
#pragma unroll
  for (int ks = 0; ks < 8; ks++) {
    const int kb = ks * 32 + lg * 8;
    bf16x8 ah[4], al[4], bh[2], bl[2];
#pragma unroll
    for (int mt = 0; mt < 4; mt++) {
      int row = mt * 16 + lr;
      int byte = row * 512 + ((kb * 2) ^ ((row & 7) << 4));
      ah[mt] = *(const bf16x8*)(sm + byte);
      al[mt] = *(const bf16x8*)(sm + EB * 512 + byte);
    }
#pragma unroll
    for (int nt = 0; nt < 2; nt++) {
      int col = nbase + nt * 16 + lr;
      bh[nt] = *(const bf16x8*)(w2t_hi + (size_t)col * HID + kb);
      bl[nt] = *(const bf16x8*)(w2t_lo + (size_t)col * HID + kb);
    }
#pragma unroll
    for (int mt = 0; mt < 4; mt++)
#pragma unroll
      for (int nt = 0; nt < 2; nt++) {
        acc[mt][nt] = __builtin_amdgcn_mfma_f32_16x16x32_bf16(ah[mt], bh[nt], acc[mt][nt], 0, 0, 0);
        acc[mt][nt] = __builtin_amdgcn_mfma_f32_16x16x32_bf16(ah[mt], bl[nt], acc[mt][nt], 0, 0, 0);
        acc[mt][nt] = __builtin_amdgcn_mfma_f32_16x16x32_bf16(al[mt], bh[nt], acc[mt][nt], 0, 0, 0);
      }
  }
  __builtin_amdgcn_s_setprio(0);
  __syncthreads();   // all hs reads done; safe to overwrite with OUT

  // ---- spill frags to LDS OUT (col bit4 swizzle keyed on row bit2) ----
  float* OUT = (float*)sm;
#pragma unroll
  for (int mt = 0; mt < 4; mt++)
#pragma unroll
    for (int nt = 0; nt < 2; nt++)
#pragma unroll
      for (int r = 0; r < 4; r++) {
        int row = mt * 16 + lg * 4 + r;
        int col = nbase + nt * 16 + lr;
        int c2 = col ^ (((row >> 2) & 1) << 4);
        OUT[row * HID + c2] = acc[mt][nt][r];
      }
  __syncthreads();

  // ---- segmented max: 2 workers per column (edge halves, R7-validated) ----
  const int half = tid >> 8;           // 0/1
  const int j = tid & 255;
  const float b2j = b2[j];
  const int elo = half * 32, ehi = elo + 32;
  const bool left_open  = (half == 0) ? true : (sdst[elo - 1] == sdst[elo]);
  const bool right_open = (half == 1) ? true : (sdst[ehi] == sdst[ehi - 1]);
  int prevd = sdst[elo];
  int segstart = elo;
  float run = -INFINITY;
  for (int e = elo; e < ehi; e++) {
    int d = sdst[e];                   // block-uniform branch
    if (d != prevd) {
      unsigned int enc = enc_f32(run + b2j);
      unsigned int* p = agg + (size_t)prevd * HID + j;
      if (segstart == elo && left_open) atomicMax(p, enc);
      else *p = enc;
      run = -INFINITY;
      segstart = e;
      prevd = d;
    }
    run = fmaxf(run, OUT[e * HID + (j ^ (((e >> 2) & 1) << 4))]);
  }
  {
    unsigned int enc = enc_f32(run + b2j);
    unsigned int* p = agg + (size_t)prevd * HID + j;
    if (right_open || (segstart == elo && left_open)) atomicMax(p, enc);
    else *p = enc;
  }
}

// ---------------- fused pooling + MLP head ----------------
__device__ __forceinline__ int lower_bound_i(const int* __restrict__ arr, int n, int val) {
  int lo = 0, hi = n;
  while (lo < hi) {
    int mid = (lo + hi) >> 1;
    if (arr[mid] < val) lo = mid + 1; else hi = mid;
  }
  return lo;
}

__global__ __launch_bounds__(256) void pool_mlp_kernel(
    const unsigned int* __restrict__ agg, const int* __restrict__ batch,
    const float* __restrict__ wc1, const float* __restrict__ bc1,
    const float* __restrict__ wc2, const float* __restrict__ bc2,
    const float* __restrict__ wc3, const float* __restrict__ bc3,
    float* __restrict__ out) {
  const int g = blockIdx.x;
  const int j = threadIdx.x;
  __shared__ float gs[2 * HID];
  __shared__ float h1[HID];
  __shared__ float h2[64];
  int s = lower_bound_i(batch, N_NODES, g);
  int e = lower_bound_i(batch, N_NODES, g + 1);
  float sum = 0.f, mx = -INFINITY;
  for (int i = s; i < e; i++) {
    float v = dec_u32(agg[(size_t)i * HID + j]);
    sum += v;
    mx = fmaxf(mx, v);
  }
  int cnt = e - s;
  gs[j] = sum / fmaxf((float)cnt, 1.f);
  gs[HID + j] = (cnt > 0) ? mx : 0.f;
  __syncthreads();
  float acc = bc1[j];
  for (int k = 0; k < 2 * HID; k++) acc = fmaf(gs[k], wc1[k * HID + j], acc);
  h1[j] = fmaxf(acc, 0.f);
  __syncthreads();
  if (j < 64) {
    float a2 = bc2[j];
    for (int k = 0; k < HID; k++) a2 = fmaf(h1[k], wc2[k * 64 + j], a2);
    h2[j] = fmaxf(a2, 0.f);
  }
  __syncthreads();
  if (j == 0) {
    float a3 = bc3[0];
    for (int k = 0; k < 64; k++) a3 = fmaf(h2[k], wc3[k], a3);
    out[g] = a3;
  }
}

extern "C" void kernel_launch(void* const* d_in, const int* in_sizes, int n_in,
                              void* d_out, int out_size, void* d_ws, size_t ws_size,
                              hipStream_t stream) {
  const float* x      = (const float*)d_in[0];
  const int*   ei     = (const int*)d_in[1];
  const int*   batch  = (const int*)d_in[2];
  const float* w1[3]  = {(const float*)d_in[3], (const float*)d_in[7],  (const float*)d_in[11]};
  const float* b1[3]  = {(const float*)d_in[4], (const float*)d_in[8],  (const float*)d_in[12]};
  const float* w2[3]  = {(const float*)d_in[5], (const float*)d_in[9],  (const float*)d_in[13]};
  const float* b2[3]  = {(const float*)d_in[6], (const float*)d_in[10], (const float*)d_in[14]};
  const float* wc1 = (const float*)d_in[15];
  const float* bc1 = (const float*)d_in[16];
  const float* wc2 = (const float*)d_in[17];
  const float* bc2 = (const float*)d_in[18];
  const float* wc3 = (const float*)d_in[19];
  const float* bc3 = (const float*)d_in[20];
  float* out = (float*)d_out;

  char* ws = (char*)d_ws;
  size_t off = 0;
  auto walloc = [&](size_t bytes) -> void* {
    void* p = ws + off;
    off += (bytes + 255) & ~(size_t)255;
    return p;
  };
  const size_t nh = (size_t)N_NODES * HID;
  float*          A       = (float*)walloc(nh * sizeof(float));
  float*          Bm      = (float*)walloc(nh * sizeof(float));
  unsigned int*   AGG     = (unsigned int*)walloc(nh * sizeof(unsigned int));
  int*            deg     = (int*)walloc((size_t)N_NODES * sizeof(int));
  int*            cursor  = (int*)walloc((size_t)N_NODES * sizeof(int));
  int*            csr_src = (int*)walloc((size_t)N_EDGES * sizeof(int));
  int*            csr_dst = (int*)walloc((size_t)N_EDGES * sizeof(int));
  unsigned short* w2t_hi  = (unsigned short*)walloc((size_t)3 * HID * HID * sizeof(unsigned short));
  unsigned short* w2t_lo  = (unsigned short*)walloc((size_t)3 * HID * HID * sizeof(unsigned short));
  unsigned short* w1t_hi  = (unsigned short*)walloc((size_t)2 * 512 * HID * sizeof(unsigned short));
  unsigned short* w1t_lo  = (unsigned short*)walloc((size_t)2 * 512 * HID * sizeof(unsigned short));
  (void)ws_size; (void)in_sizes; (void)n_in; (void)out_size;

  // ---- one-time: weight prep + CSR build ----
  hipMemsetAsync(deg, 0, N_NODES * sizeof(int), stream);
  prep_weights_kernel<<<1792, 256, 0, stream>>>(w2[0], w2[1], w2[2], w1[1], w1[2],
                                                w2t_hi, w2t_lo, w1t_hi, w1t_lo);
  hist_kernel<<<(N_EDGES + 255) / 256, 256, 0, stream>>>(ei, deg);
  scan_kernel<<<1, 256, 0, stream>>>(deg, cursor);
  scatter_kernel<<<(N_EDGES + 255) / 256, 256, 0, stream>>>(ei, cursor, csr_src, csr_dst);

  for (int l = 0; l < 3; l++) {
    if (l == 0)
      node_ab_l0_kernel<<<N_NODES / 32, 256, 0, stream>>>(x, w1[0], b1[0], A, Bm);
    else
      node_mfma_kernel<<<(N_NODES + NBK - 1) / NBK, 512, 0, stream>>>(
          AGG, w1t_hi + (size_t)(l - 1) * 512 * HID, w1t_lo + (size_t)(l - 1) * 512 * HID,
          b1[l], A, Bm);
    hipMemsetAsync(AGG, 0, nh * sizeof(unsigned int), stream);
    edge_mfma_kernel<<<NB, 512, 0, stream>>>(csr_src, csr_dst, A, Bm,
                                             w2t_hi + (size_t)l * HID * HID,
                                             w2t_lo + (size_t)l * HID * HID,
                                             b2[l], AGG);
  }
  pool_mlp_kernel<<<N_GRAPHS, 256, 0, stream>>>(AGG, batch, wc1, bc1, wc2, bc2, wc3, bc3, out);
}